// Round 3
// baseline (1283.462 us; speedup 1.0000x reference)
//
#include <hip/hip_runtime.h>
#include <cstdint>

__device__ __forceinline__ float lrelu02(float x) {
    return fmaxf(x, 0.f) + 0.2f * fminf(x, 0.f);
}

// ---------------------------------------------------------------------------
// LN row stats for x_patent rows of length 256: one wave per row
// ---------------------------------------------------------------------------
__global__ __launch_bounds__(256) void ln_stats_kernel(
    const float* __restrict__ x, float* __restrict__ mean, float* __restrict__ rstd, int n)
{
    int wid  = (blockIdx.x * blockDim.x + threadIdx.x) >> 6;
    int lane = threadIdx.x & 63;
    if (wid >= n) return;
    float4 v = *reinterpret_cast<const float4*>(x + (size_t)wid * 256 + lane * 4);
    float s = v.x + v.y + v.z + v.w;
    float q = v.x * v.x + v.y * v.y + v.z * v.z + v.w * v.w;
    #pragma unroll
    for (int m = 32; m >= 1; m >>= 1) {
        s += __shfl_xor(s, m);
        q += __shfl_xor(q, m);
    }
    if (lane == 0) {
        float mu  = s * (1.0f / 256.0f);
        float var = q * (1.0f / 256.0f) - mu * mu;
        mean[wid] = mu;
        rstd[wid] = rsqrtf(var + 1e-5f);
    }
}

// ---------------------------------------------------------------------------
// CSR build: zero, histogram, single-block scan, scatter
// ---------------------------------------------------------------------------
__global__ void zero_int_kernel(int* __restrict__ p, int n) {
    int i = blockIdx.x * blockDim.x + threadIdx.x;
    if (i < n) p[i] = 0;
}

__global__ void hist_kernel(const int* __restrict__ dst, int* __restrict__ deg, int ec) {
    int i = blockIdx.x * blockDim.x + threadIdx.x;
    if (i < ec) atomicAdd(&deg[dst[i]], 1);
}

__global__ __launch_bounds__(1024) void scan_kernel(
    const int* __restrict__ deg, int* __restrict__ rowptr, int* __restrict__ cursor, int n)
{
    __shared__ int part[1024];
    int t = threadIdx.x;
    int chunk = (n + 1023) >> 10;
    int lo = t * chunk;
    int hi = min(lo + chunk, n);
    int s = 0;
    for (int i = lo; i < hi; ++i) s += deg[i];
    part[t] = s;
    __syncthreads();
    for (int off = 1; off < 1024; off <<= 1) {
        int v = (t >= off) ? part[t - off] : 0;
        __syncthreads();
        part[t] += v;
        __syncthreads();
    }
    int run = part[t] - s;   // exclusive prefix
    for (int i = lo; i < hi; ++i) {
        rowptr[i] = run;
        cursor[i] = run;
        run += deg[i];
    }
    if (t == 1023) rowptr[n] = part[1023];
}

__global__ void scatter_kernel(const int* __restrict__ src, const int* __restrict__ dst,
                               int* __restrict__ cursor, int* __restrict__ esrc, int ec)
{
    int i = blockIdx.x * blockDim.x + threadIdx.x;
    if (i < ec) {
        int d = dst[i];
        int pos = atomicAdd(&cursor[d], 1);
        esrc[pos] = src[i];
    }
}

// ---------------------------------------------------------------------------
// Tiled fp32 GEMM: Y[n,128] = op(X[n,K]) @ W[K,128] (+ bias)
// op = LayerNorm-on-load when LN_IN (per-row mean/rstd + per-col gamma/beta)
// ESED: also emit es/ed attention scalars from the accumulator tile.
// BM=64, BN=128, BK=64, 256 threads, 8x4 accs/thread.
// ---------------------------------------------------------------------------
template <int K, bool LN_IN, bool BIAS, bool ESED>
__global__ __launch_bounds__(256) void gemm_kernel(
    const float* __restrict__ X, const float* __restrict__ W, const float* __restrict__ bias,
    const float* __restrict__ mean, const float* __restrict__ rstd,
    const float* __restrict__ gw, const float* __restrict__ gb,
    const float* __restrict__ a_s, const float* __restrict__ a_d,
    float* __restrict__ es, float* __restrict__ ed,
    float* __restrict__ Y, int n)
{
    __shared__ float xs[64 * 68];    // 64 rows x 64 k, stride 68
    __shared__ float ws[64 * 132];   // 64 k  x 128 cols, stride 132
    int t  = threadIdx.x;
    int tx = t & 31;        // col group: cols tx*4 .. tx*4+3
    int ty = t >> 5;        // row group: rows ty*8 .. ty*8+7
    int row0 = blockIdx.x * 64;

    float acc[8][4];
    #pragma unroll
    for (int i = 0; i < 8; ++i)
        #pragma unroll
        for (int j = 0; j < 4; ++j) acc[i][j] = 0.f;

    for (int kt = 0; kt < K / 64; ++kt) {
        // X tile: 64x64 = 1024 float4
        #pragma unroll
        for (int i = 0; i < 4; ++i) {
            int fi = t + 256 * i;
            int r  = fi >> 4;
            int c  = (fi & 15) * 4;
            int gr = row0 + r;
            float4 v = make_float4(0.f, 0.f, 0.f, 0.f);
            if (gr < n) {
                v = *reinterpret_cast<const float4*>(X + (size_t)gr * K + kt * 64 + c);
                if (LN_IN) {
                    float mu = mean[gr];
                    float rs = rstd[gr];
                    float4 w4 = *reinterpret_cast<const float4*>(gw + kt * 64 + c);
                    float4 b4 = *reinterpret_cast<const float4*>(gb + kt * 64 + c);
                    v.x = (v.x - mu) * rs * w4.x + b4.x;
                    v.y = (v.y - mu) * rs * w4.y + b4.y;
                    v.z = (v.z - mu) * rs * w4.z + b4.z;
                    v.w = (v.w - mu) * rs * w4.w + b4.w;
                }
            }
            *reinterpret_cast<float4*>(&xs[r * 68 + c]) = v;
        }
        // W tile: 64x128 = 2048 float4
        #pragma unroll
        for (int i = 0; i < 8; ++i) {
            int fi = t + 256 * i;
            int r  = fi >> 5;
            int c  = (fi & 31) * 4;
            float4 v = *reinterpret_cast<const float4*>(W + (size_t)(kt * 64 + r) * 128 + c);
            *reinterpret_cast<float4*>(&ws[r * 132 + c]) = v;
        }
        __syncthreads();

        #pragma unroll
        for (int kk = 0; kk < 64; kk += 4) {
            float4 a4[8];
            #pragma unroll
            for (int i = 0; i < 8; ++i)
                a4[i] = *reinterpret_cast<const float4*>(&xs[(ty * 8 + i) * 68 + kk]);
            #pragma unroll
            for (int u = 0; u < 4; ++u) {
                float4 b = *reinterpret_cast<const float4*>(&ws[(kk + u) * 132 + tx * 4]);
                #pragma unroll
                for (int i = 0; i < 8; ++i) {
                    float a = (u == 0) ? a4[i].x : (u == 1) ? a4[i].y : (u == 2) ? a4[i].z : a4[i].w;
                    acc[i][0] = fmaf(a, b.x, acc[i][0]);
                    acc[i][1] = fmaf(a, b.y, acc[i][1]);
                    acc[i][2] = fmaf(a, b.z, acc[i][2]);
                    acc[i][3] = fmaf(a, b.w, acc[i][3]);
                }
            }
        }
        __syncthreads();
    }

    float4 bb = make_float4(0.f, 0.f, 0.f, 0.f);
    if (BIAS) bb = *reinterpret_cast<const float4*>(bias + tx * 4);
    #pragma unroll
    for (int i = 0; i < 8; ++i) {
        int gr = row0 + ty * 8 + i;
        if (gr < n) {
            float4 o;
            o.x = acc[i][0] + bb.x;
            o.y = acc[i][1] + bb.y;
            o.z = acc[i][2] + bb.z;
            o.w = acc[i][3] + bb.w;
            *reinterpret_cast<float4*>(Y + (size_t)gr * 128 + tx * 4) = o;
        }
    }

    if (ESED) {
        // es[n,4] / ed[n,4]: per-head dot of the row with a_s/a_d.
        // Thread covers cols tx*4..tx*4+3, head = tx>>3; reduce over the 8
        // lanes (tx&7) sharing a head via shfl (lane bits 0..2 == tx bits 0..2).
        float4 as4 = *reinterpret_cast<const float4*>(a_s + tx * 4);
        float4 ad4 = *reinterpret_cast<const float4*>(a_d + tx * 4);
        #pragma unroll
        for (int i = 0; i < 8; ++i) {
            float ps = acc[i][0] * as4.x + acc[i][1] * as4.y + acc[i][2] * as4.z + acc[i][3] * as4.w;
            float pd = acc[i][0] * ad4.x + acc[i][1] * ad4.y + acc[i][2] * ad4.z + acc[i][3] * ad4.w;
            #pragma unroll
            for (int m = 1; m <= 4; m <<= 1) {
                ps += __shfl_xor(ps, m);
                pd += __shfl_xor(pd, m);
            }
            int gr = row0 + ty * 8 + i;
            if ((tx & 7) == 0 && gr < n) {
                es[(size_t)gr * 4 + (tx >> 3)] = ps;
                ed[(size_t)gr * 4 + (tx >> 3)] = pd;
            }
        }
    }
}

// ---------------------------------------------------------------------------
// GAT aggregation, two-phase with lane-parallel edges, fused +bias, relu,
// LayerNorm, +residual. One wave per dst node.
// Lane l: head h = l>>4, edge-slot sub = l&15, owns output cols 2l, 2l+1.
// ---------------------------------------------------------------------------
__global__ __launch_bounds__(256) void gat_aggregate_kernel(
    const float* __restrict__ xph, const float* __restrict__ es, const float* __restrict__ ed,
    const int* __restrict__ rowptr, const int* __restrict__ esrc,
    const float* __restrict__ gbias, const float* __restrict__ lnw, const float* __restrict__ lnb,
    float* __restrict__ xp, int n)
{
    int d = (blockIdx.x * blockDim.x + threadIdx.x) >> 6;
    int l = threadIdx.x & 63;
    if (d >= n) return;
    int h   = l >> 4;
    int sub = l & 15;

    float edh   = ed[(size_t)d * 4 + h];
    float eself = lrelu02(es[(size_t)d * 4 + h] + edh);

    int jb = rowptr[d], je = rowptr[d + 1];

    // ---- phase 1: per-head max, lane-parallel (each lane strides by 16)
    float mh = eself;
    for (int j = jb + sub; j < je; j += 16) {
        int s = esrc[j];
        mh = fmaxf(mh, lrelu02(es[(size_t)s * 4 + h] + edh));
    }
    #pragma unroll
    for (int mm = 1; mm <= 8; mm <<= 1) mh = fmaxf(mh, __shfl_xor(mh, mm));
    // mh now uniform within each 16-lane head group

    // ---- phase 2: weights (1 exp per lane per 16-edge batch) + gather
    float wself = __expf(eself - mh);
    float2 xd   = *reinterpret_cast<const float2*>(xph + (size_t)d * 128 + 2 * l);
    float2 acc  = make_float2(wself * xd.x, wself * xd.y);
    float  wsum = wself;

    int j0 = jb;
    for (; j0 + 16 <= je; j0 += 16) {
        int   myS = esrc[j0 + sub];
        float wl  = __expf(lrelu02(es[(size_t)myS * 4 + h] + edh) - mh);
        #pragma unroll
        for (int u = 0; u < 16; ++u) {
            int   s  = __shfl(myS, u);                  // uniform across wave
            float wj = __shfl(wl, (l & 48) + u);        // own head's weight
            float2 xv = *reinterpret_cast<const float2*>(xph + (size_t)s * 128 + 2 * l);
            wsum += wj;
            acc.x = fmaf(wj, xv.x, acc.x);
            acc.y = fmaf(wj, xv.y, acc.y);
        }
    }
    if (j0 < je) {
        int   cnt = je - j0;                            // 1..15, wave-uniform
        int   myj = j0 + ((sub < cnt) ? sub : 0);       // clamp to valid edge
        int   myS = esrc[myj];
        float wl  = (sub < cnt)
                  ? __expf(lrelu02(es[(size_t)myS * 4 + h] + edh) - mh) : 0.f;
        for (int u = 0; u < cnt; ++u) {
            int   s  = __shfl(myS, u);
            float wj = __shfl(wl, (l & 48) + u);
            float2 xv = *reinterpret_cast<const float2*>(xph + (size_t)s * 128 + 2 * l);
            wsum += wj;
            acc.x = fmaf(wj, xv.x, acc.x);
            acc.y = fmaf(wj, xv.y, acc.y);
        }
    }

    float inv = 1.0f / (wsum + 1e-16f);
    float2 gb2 = *reinterpret_cast<const float2*>(gbias + 2 * l);
    float v0 = fmaxf(fmaf(acc.x, inv, gb2.x), 0.f);
    float v1 = fmaxf(fmaf(acc.y, inv, gb2.y), 0.f);

    // LayerNorm over 128 (2 values/lane across the wave) + residual
    float sum = v0 + v1;
    float sq  = v0 * v0 + v1 * v1;
    #pragma unroll
    for (int mm = 32; mm >= 1; mm >>= 1) {
        sum += __shfl_xor(sum, mm);
        sq  += __shfl_xor(sq, mm);
    }
    float mu  = sum * (1.0f / 128.0f);
    float var = sq * (1.0f / 128.0f) - mu * mu;
    float rs  = rsqrtf(var + 1e-5f);
    float2 w2 = *reinterpret_cast<const float2*>(lnw + 2 * l);
    float2 b2 = *reinterpret_cast<const float2*>(lnb + 2 * l);
    float2 xin = *reinterpret_cast<const float2*>(xp + (size_t)d * 128 + 2 * l);
    float o0 = (v0 - mu) * rs * w2.x + b2.x + xin.x;
    float o1 = (v1 - mu) * rs * w2.y + b2.y + xin.y;
    *reinterpret_cast<float2*>(xp + (size_t)d * 128 + 2 * l) = make_float2(o0, o1);
}

// ---------------------------------------------------------------------------
// Classifier: out = relu(X @ c1W + c1b) @ c2W + c2b. One wave per row,
// c1W (32KB) + c2W staged in LDS per block, grid-stride over rows.
// ---------------------------------------------------------------------------
__global__ __launch_bounds__(256) void classifier_kernel(
    const float* __restrict__ X, const float* __restrict__ c1W, const float* __restrict__ c1b,
    const float* __restrict__ c2W, const float* __restrict__ c2b,
    float* __restrict__ out, int n)
{
    __shared__ float w1[128 * 64];
    __shared__ float w2[64 * 8];
    __shared__ float b1s[64];
    __shared__ float b2s[8];
    int t = threadIdx.x;
    #pragma unroll
    for (int i = 0; i < 8; ++i) {
        int fi = t + 256 * i;   // 2048 float4 total
        *reinterpret_cast<float4*>(&w1[fi * 4]) = reinterpret_cast<const float4*>(c1W)[fi];
    }
    if (t < 128) reinterpret_cast<float4*>(w2)[t] = reinterpret_cast<const float4*>(c2W)[t];
    if (t < 64)  b1s[t] = c1b[t];
    if (t < 8)   b2s[t] = c2b[t];
    __syncthreads();

    int nw = gridDim.x * 4;
    int w  = blockIdx.x * 4 + (t >> 6);
    int j  = t & 63;
    for (int r = w; r < n; r += nw) {
        float hacc = b1s[j];
        #pragma unroll 8
        for (int k4 = 0; k4 < 32; ++k4) {
            float4 xv = *reinterpret_cast<const float4*>(X + (size_t)r * 128 + k4 * 4);
            hacc = fmaf(xv.x, w1[(k4 * 4 + 0) * 64 + j], hacc);
            hacc = fmaf(xv.y, w1[(k4 * 4 + 1) * 64 + j], hacc);
            hacc = fmaf(xv.z, w1[(k4 * 4 + 2) * 64 + j], hacc);
            hacc = fmaf(xv.w, w1[(k4 * 4 + 3) * 64 + j], hacc);
        }
        hacc = fmaxf(hacc, 0.f);
        float p[8];
        #pragma unroll
        for (int o = 0; o < 8; ++o) p[o] = hacc * w2[j * 8 + o];
        #pragma unroll
        for (int mm = 32; mm >= 1; mm >>= 1) {
            #pragma unroll
            for (int o = 0; o < 8; ++o) p[o] += __shfl_xor(p[o], mm);
        }
        float po = p[0];
        #pragma unroll
        for (int o = 1; o < 8; ++o) po = (j == o) ? p[o] : po;
        if (j < 8) out[(size_t)r * 8 + j] = po + b2s[j];
    }
}

// ---------------------------------------------------------------------------
extern "C" void kernel_launch(void* const* d_in, const int* in_sizes, int n_in,
                              void* d_out, int out_size, void* d_ws, size_t ws_size,
                              hipStream_t stream)
{
    const float* x_patent = (const float*)d_in[0];
    const int*   ei_cites = (const int*)d_in[2];
    const float* pn_w = (const float*)d_in[4];
    const float* pn_b = (const float*)d_in[5];
    const float* pl_W = (const float*)d_in[8];
    const float* pl_b = (const float*)d_in[9];
    const float* g1_W  = (const float*)d_in[12];
    const float* g1_as = (const float*)d_in[13];
    const float* g1_ad = (const float*)d_in[14];
    const float* g1_b  = (const float*)d_in[15];
    const float* g2_W  = (const float*)d_in[16];
    const float* g2_as = (const float*)d_in[17];
    const float* g2_ad = (const float*)d_in[18];
    const float* g2_b  = (const float*)d_in[19];
    const float* n1_w = (const float*)d_in[23];
    const float* n1_b = (const float*)d_in[24];
    const float* n3_w = (const float*)d_in[27];
    const float* n3_b = (const float*)d_in[28];
    const float* c1_W = (const float*)d_in[29];
    const float* c1_b = (const float*)d_in[30];
    const float* c2_W = (const float*)d_in[31];
    const float* c2_b = (const float*)d_in[32];

    const int NP = in_sizes[0] / 256;   // 100000
    const int EC = in_sizes[2] / 2;     // 1600000
    const int* e_src = ei_cites;
    const int* e_dst = ei_cites + EC;

    // workspace layout
    size_t off = 0;
    auto alloc = [&](size_t bytes) -> char* {
        char* p = (char*)d_ws + off;
        off += (bytes + 255) & ~(size_t)255;
        return p;
    };
    float* xp     = (float*)alloc((size_t)NP * 128 * 4);
    float* xph    = (float*)alloc((size_t)NP * 128 * 4);
    float* es     = (float*)alloc((size_t)NP * 4 * 4);
    float* ed     = (float*)alloc((size_t)NP * 4 * 4);
    float* meanb  = (float*)alloc((size_t)NP * 4);
    float* rstdb  = (float*)alloc((size_t)NP * 4);
    int*   deg    = (int*)alloc((size_t)NP * 4);
    int*   rowptr = (int*)alloc((size_t)(NP + 1) * 4);
    int*   cursor = (int*)alloc((size_t)NP * 4);
    int*   esrc   = (int*)alloc((size_t)EC * 4);
    (void)ws_size; (void)n_in; (void)out_size;

    int wpgrid = (NP + 3) / 4;            // wave-per-row kernels, 4 waves/block
    int egrid  = (EC + 255) / 256;
    int ggrid  = (NP + 63) / 64;

    // --- CSR build (shared by both GAT layers)
    zero_int_kernel<<<(NP + 255) / 256, 256, 0, stream>>>(deg, NP);
    hist_kernel<<<egrid, 256, 0, stream>>>(e_dst, deg, EC);
    scan_kernel<<<1, 1024, 0, stream>>>(deg, rowptr, cursor, NP);
    scatter_kernel<<<egrid, 256, 0, stream>>>(e_src, e_dst, cursor, esrc, EC);

    // --- xp = LN(x_patent) @ pl_W + pl_b
    ln_stats_kernel<<<wpgrid, 256, 0, stream>>>(x_patent, meanb, rstdb, NP);
    gemm_kernel<256, true, true, false><<<ggrid, 256, 0, stream>>>(
        x_patent, pl_W, pl_b, meanb, rstdb, pn_w, pn_b,
        nullptr, nullptr, nullptr, nullptr, xp, NP);

    // --- GAT layer 1 + relu + LN(n1) + residual (in place on xp)
    gemm_kernel<128, false, false, true><<<ggrid, 256, 0, stream>>>(
        xp, g1_W, nullptr, nullptr, nullptr, nullptr, nullptr,
        g1_as, g1_ad, es, ed, xph, NP);
    gat_aggregate_kernel<<<wpgrid, 256, 0, stream>>>(
        xph, es, ed, rowptr, esrc, g1_b, n1_w, n1_b, xp, NP);

    // --- GAT layer 2 + relu + LN(n3) + residual (in place on xp)
    gemm_kernel<128, false, false, true><<<ggrid, 256, 0, stream>>>(
        xp, g2_W, nullptr, nullptr, nullptr, nullptr, nullptr,
        g2_as, g2_ad, es, ed, xph, NP);
    gat_aggregate_kernel<<<wpgrid, 256, 0, stream>>>(
        xph, es, ed, rowptr, esrc, g2_b, n3_w, n3_b, xp, NP);

    // --- classifier head
    classifier_kernel<<<1024, 256, 0, stream>>>(
        xp, c1_W, c1_b, c2_W, c2_b, (float*)d_out, NP);
}

// Round 4
// 1067.640 us; speedup vs baseline: 1.2021x; 1.2021x over previous
//
#include <hip/hip_runtime.h>
#include <cstdint>

__device__ __forceinline__ float lrelu02(float x) {
    return fmaxf(x, 0.f) + 0.2f * fminf(x, 0.f);
}

// ---------------------------------------------------------------------------
// LN row stats for x_patent rows of length 256: one wave per row
// ---------------------------------------------------------------------------
__global__ __launch_bounds__(256) void ln_stats_kernel(
    const float* __restrict__ x, float* __restrict__ mean, float* __restrict__ rstd, int n)
{
    int wid  = (blockIdx.x * blockDim.x + threadIdx.x) >> 6;
    int lane = threadIdx.x & 63;
    if (wid >= n) return;
    float4 v = *reinterpret_cast<const float4*>(x + (size_t)wid * 256 + lane * 4);
    float s = v.x + v.y + v.z + v.w;
    float q = v.x * v.x + v.y * v.y + v.z * v.z + v.w * v.w;
    #pragma unroll
    for (int m = 32; m >= 1; m >>= 1) {
        s += __shfl_xor(s, m);
        q += __shfl_xor(q, m);
    }
    if (lane == 0) {
        float mu  = s * (1.0f / 256.0f);
        float var = q * (1.0f / 256.0f) - mu * mu;
        mean[wid] = mu;
        rstd[wid] = rsqrtf(var + 1e-5f);
    }
}

// ---------------------------------------------------------------------------
// CSR build: zero, histogram, 3-phase hierarchical scan, scatter
// ---------------------------------------------------------------------------
__global__ void zero_int_kernel(int* __restrict__ p, int n) {
    int i = blockIdx.x * blockDim.x + threadIdx.x;
    if (i < n) p[i] = 0;
}

__global__ void hist_kernel(const int* __restrict__ dst, int* __restrict__ deg, int ec) {
    int i = blockIdx.x * blockDim.x + threadIdx.x;
    if (i < ec) atomicAdd(&deg[dst[i]], 1);
}

// phase 1: per-1024-block local exclusive scan + block totals
__global__ __launch_bounds__(1024) void scan_blocks_kernel(
    const int* __restrict__ deg, int* __restrict__ rowptr, int* __restrict__ partials, int n)
{
    __shared__ int part[1024];
    int t = threadIdx.x;
    int i = blockIdx.x * 1024 + t;
    int v = (i < n) ? deg[i] : 0;
    part[t] = v;
    __syncthreads();
    #pragma unroll
    for (int off = 1; off < 1024; off <<= 1) {
        int u = (t >= off) ? part[t - off] : 0;
        __syncthreads();
        part[t] += u;
        __syncthreads();
    }
    if (i < n) rowptr[i] = part[t] - v;          // local exclusive prefix
    if (t == 1023) partials[blockIdx.x] = part[1023];
}

// phase 2: single small block scans the partials (nb <= 128)
__global__ __launch_bounds__(128) void scan_partials_kernel(
    int* __restrict__ partials, int* __restrict__ rowptr, int nb, int n)
{
    __shared__ int p[128];
    int t = threadIdx.x;
    int v = (t < nb) ? partials[t] : 0;
    p[t] = v;
    __syncthreads();
    #pragma unroll
    for (int off = 1; off < 128; off <<= 1) {
        int u = (t >= off) ? p[t - off] : 0;
        __syncthreads();
        p[t] += u;
        __syncthreads();
    }
    if (t < nb) partials[t] = p[t] - v;          // exclusive block offsets
    if (t == 127) rowptr[n] = p[127];            // total edge count
}

// phase 3: add block offsets; mirror into cursor
__global__ __launch_bounds__(1024) void add_offsets_kernel(
    const int* __restrict__ partials, int* __restrict__ rowptr, int* __restrict__ cursor, int n)
{
    int i = blockIdx.x * 1024 + threadIdx.x;
    if (i < n) {
        int r = rowptr[i] + partials[blockIdx.x];
        rowptr[i] = r;
        cursor[i] = r;
    }
}

__global__ void scatter_kernel(const int* __restrict__ src, const int* __restrict__ dst,
                               int* __restrict__ cursor, int* __restrict__ esrc, int ec)
{
    int i = blockIdx.x * blockDim.x + threadIdx.x;
    if (i < ec) {
        int d = dst[i];
        int pos = atomicAdd(&cursor[d], 1);
        esrc[pos] = src[i];
    }
}

// ---------------------------------------------------------------------------
// Tiled fp32 GEMM: Y[n,128] = op(X[n,K]) @ W[K,128] (+ bias)
// op = LayerNorm-on-load when LN_IN (per-row mean/rstd + per-col gamma/beta)
// ESED: also emit es/ed attention scalars from the accumulator tile.
// BM=64, BN=128, BK=64, 256 threads, 8x4 accs/thread.
// ---------------------------------------------------------------------------
template <int K, bool LN_IN, bool BIAS, bool ESED>
__global__ __launch_bounds__(256) void gemm_kernel(
    const float* __restrict__ X, const float* __restrict__ W, const float* __restrict__ bias,
    const float* __restrict__ mean, const float* __restrict__ rstd,
    const float* __restrict__ gw, const float* __restrict__ gb,
    const float* __restrict__ a_s, const float* __restrict__ a_d,
    float* __restrict__ es, float* __restrict__ ed,
    float* __restrict__ Y, int n)
{
    __shared__ float xs[64 * 68];    // 64 rows x 64 k, stride 68
    __shared__ float ws[64 * 132];   // 64 k  x 128 cols, stride 132
    int t  = threadIdx.x;
    int tx = t & 31;        // col group: cols tx*4 .. tx*4+3
    int ty = t >> 5;        // row group: rows ty*8 .. ty*8+7
    int row0 = blockIdx.x * 64;

    float acc[8][4];
    #pragma unroll
    for (int i = 0; i < 8; ++i)
        #pragma unroll
        for (int j = 0; j < 4; ++j) acc[i][j] = 0.f;

    for (int kt = 0; kt < K / 64; ++kt) {
        // X tile: 64x64 = 1024 float4
        #pragma unroll
        for (int i = 0; i < 4; ++i) {
            int fi = t + 256 * i;
            int r  = fi >> 4;
            int c  = (fi & 15) * 4;
            int gr = row0 + r;
            float4 v = make_float4(0.f, 0.f, 0.f, 0.f);
            if (gr < n) {
                v = *reinterpret_cast<const float4*>(X + (size_t)gr * K + kt * 64 + c);
                if (LN_IN) {
                    float mu = mean[gr];
                    float rs = rstd[gr];
                    float4 w4 = *reinterpret_cast<const float4*>(gw + kt * 64 + c);
                    float4 b4 = *reinterpret_cast<const float4*>(gb + kt * 64 + c);
                    v.x = (v.x - mu) * rs * w4.x + b4.x;
                    v.y = (v.y - mu) * rs * w4.y + b4.y;
                    v.z = (v.z - mu) * rs * w4.z + b4.z;
                    v.w = (v.w - mu) * rs * w4.w + b4.w;
                }
            }
            *reinterpret_cast<float4*>(&xs[r * 68 + c]) = v;
        }
        // W tile: 64x128 = 2048 float4
        #pragma unroll
        for (int i = 0; i < 8; ++i) {
            int fi = t + 256 * i;
            int r  = fi >> 5;
            int c  = (fi & 31) * 4;
            float4 v = *reinterpret_cast<const float4*>(W + (size_t)(kt * 64 + r) * 128 + c);
            *reinterpret_cast<float4*>(&ws[r * 132 + c]) = v;
        }
        __syncthreads();

        #pragma unroll
        for (int kk = 0; kk < 64; kk += 4) {
            float4 a4[8];
            #pragma unroll
            for (int i = 0; i < 8; ++i)
                a4[i] = *reinterpret_cast<const float4*>(&xs[(ty * 8 + i) * 68 + kk]);
            #pragma unroll
            for (int u = 0; u < 4; ++u) {
                float4 b = *reinterpret_cast<const float4*>(&ws[(kk + u) * 132 + tx * 4]);
                #pragma unroll
                for (int i = 0; i < 8; ++i) {
                    float a = (u == 0) ? a4[i].x : (u == 1) ? a4[i].y : (u == 2) ? a4[i].z : a4[i].w;
                    acc[i][0] = fmaf(a, b.x, acc[i][0]);
                    acc[i][1] = fmaf(a, b.y, acc[i][1]);
                    acc[i][2] = fmaf(a, b.z, acc[i][2]);
                    acc[i][3] = fmaf(a, b.w, acc[i][3]);
                }
            }
        }
        __syncthreads();
    }

    float4 bb = make_float4(0.f, 0.f, 0.f, 0.f);
    if (BIAS) bb = *reinterpret_cast<const float4*>(bias + tx * 4);
    #pragma unroll
    for (int i = 0; i < 8; ++i) {
        int gr = row0 + ty * 8 + i;
        if (gr < n) {
            float4 o;
            o.x = acc[i][0] + bb.x;
            o.y = acc[i][1] + bb.y;
            o.z = acc[i][2] + bb.z;
            o.w = acc[i][3] + bb.w;
            *reinterpret_cast<float4*>(Y + (size_t)gr * 128 + tx * 4) = o;
        }
    }

    if (ESED) {
        // es[n,4] / ed[n,4]: per-head dot of the row with a_s/a_d.
        // Thread covers cols tx*4..tx*4+3, head = tx>>3; reduce over the 8
        // lanes (tx&7) sharing a head via shfl (lane bits 0..2 == tx bits 0..2).
        float4 as4 = *reinterpret_cast<const float4*>(a_s + tx * 4);
        float4 ad4 = *reinterpret_cast<const float4*>(a_d + tx * 4);
        #pragma unroll
        for (int i = 0; i < 8; ++i) {
            float ps = acc[i][0] * as4.x + acc[i][1] * as4.y + acc[i][2] * as4.z + acc[i][3] * as4.w;
            float pd = acc[i][0] * ad4.x + acc[i][1] * ad4.y + acc[i][2] * ad4.z + acc[i][3] * ad4.w;
            #pragma unroll
            for (int m = 1; m <= 4; m <<= 1) {
                ps += __shfl_xor(ps, m);
                pd += __shfl_xor(pd, m);
            }
            int gr = row0 + ty * 8 + i;
            if ((tx & 7) == 0 && gr < n) {
                es[(size_t)gr * 4 + (tx >> 3)] = ps;
                ed[(size_t)gr * 4 + (tx >> 3)] = pd;
            }
        }
    }
}

// ---------------------------------------------------------------------------
// GAT aggregation, two-phase with lane-parallel edges, fused +bias, relu,
// LayerNorm, +residual. One wave per dst node.
// Lane l: head h = l>>4, edge-slot sub = l&15, owns output cols 2l, 2l+1.
// ---------------------------------------------------------------------------
__global__ __launch_bounds__(256) void gat_aggregate_kernel(
    const float* __restrict__ xph, const float* __restrict__ es, const float* __restrict__ ed,
    const int* __restrict__ rowptr, const int* __restrict__ esrc,
    const float* __restrict__ gbias, const float* __restrict__ lnw, const float* __restrict__ lnb,
    float* __restrict__ xp, int n)
{
    int d = (blockIdx.x * blockDim.x + threadIdx.x) >> 6;
    int l = threadIdx.x & 63;
    if (d >= n) return;
    int h   = l >> 4;
    int sub = l & 15;

    float edh   = ed[(size_t)d * 4 + h];
    float eself = lrelu02(es[(size_t)d * 4 + h] + edh);

    int jb = rowptr[d], je = rowptr[d + 1];

    // ---- phase 1: per-head max, lane-parallel (each lane strides by 16)
    float mh = eself;
    for (int j = jb + sub; j < je; j += 16) {
        int s = esrc[j];
        mh = fmaxf(mh, lrelu02(es[(size_t)s * 4 + h] + edh));
    }
    #pragma unroll
    for (int mm = 1; mm <= 8; mm <<= 1) mh = fmaxf(mh, __shfl_xor(mh, mm));
    // mh now uniform within each 16-lane head group

    // ---- phase 2: weights (1 exp per lane per 16-edge batch) + gather
    float wself = __expf(eself - mh);
    float2 xd   = *reinterpret_cast<const float2*>(xph + (size_t)d * 128 + 2 * l);
    float2 acc  = make_float2(wself * xd.x, wself * xd.y);
    float  wsum = wself;

    int j0 = jb;
    for (; j0 + 16 <= je; j0 += 16) {
        int   myS = esrc[j0 + sub];
        float wl  = __expf(lrelu02(es[(size_t)myS * 4 + h] + edh) - mh);
        #pragma unroll
        for (int u = 0; u < 16; ++u) {
            int   s  = __shfl(myS, u);                  // uniform across wave
            float wj = __shfl(wl, (l & 48) + u);        // own head's weight
            float2 xv = *reinterpret_cast<const float2*>(xph + (size_t)s * 128 + 2 * l);
            wsum += wj;
            acc.x = fmaf(wj, xv.x, acc.x);
            acc.y = fmaf(wj, xv.y, acc.y);
        }
    }
    if (j0 < je) {
        int   cnt = je - j0;                            // 1..15, wave-uniform
        int   myj = j0 + ((sub < cnt) ? sub : 0);       // clamp to valid edge
        int   myS = esrc[myj];
        float wl  = (sub < cnt)
                  ? __expf(lrelu02(es[(size_t)myS * 4 + h] + edh) - mh) : 0.f;
        for (int u = 0; u < cnt; ++u) {
            int   s  = __shfl(myS, u);
            float wj = __shfl(wl, (l & 48) + u);
            float2 xv = *reinterpret_cast<const float2*>(xph + (size_t)s * 128 + 2 * l);
            wsum += wj;
            acc.x = fmaf(wj, xv.x, acc.x);
            acc.y = fmaf(wj, xv.y, acc.y);
        }
    }

    float inv = 1.0f / (wsum + 1e-16f);
    float2 gb2 = *reinterpret_cast<const float2*>(gbias + 2 * l);
    float v0 = fmaxf(fmaf(acc.x, inv, gb2.x), 0.f);
    float v1 = fmaxf(fmaf(acc.y, inv, gb2.y), 0.f);

    // LayerNorm over 128 (2 values/lane across the wave) + residual
    float sum = v0 + v1;
    float sq  = v0 * v0 + v1 * v1;
    #pragma unroll
    for (int mm = 32; mm >= 1; mm >>= 1) {
        sum += __shfl_xor(sum, mm);
        sq  += __shfl_xor(sq, mm);
    }
    float mu  = sum * (1.0f / 128.0f);
    float var = sq * (1.0f / 128.0f) - mu * mu;
    float rs  = rsqrtf(var + 1e-5f);
    float2 w2 = *reinterpret_cast<const float2*>(lnw + 2 * l);
    float2 b2 = *reinterpret_cast<const float2*>(lnb + 2 * l);
    float2 xin = *reinterpret_cast<const float2*>(xp + (size_t)d * 128 + 2 * l);
    float o0 = (v0 - mu) * rs * w2.x + b2.x + xin.x;
    float o1 = (v1 - mu) * rs * w2.y + b2.y + xin.y;
    *reinterpret_cast<float2*>(xp + (size_t)d * 128 + 2 * l) = make_float2(o0, o1);
}

// ---------------------------------------------------------------------------
// Classifier: out = relu(X @ c1W + c1b) @ c2W + c2b. One wave per row,
// c1W (32KB) + c2W staged in LDS per block, grid-stride over rows.
// ---------------------------------------------------------------------------
__global__ __launch_bounds__(256) void classifier_kernel(
    const float* __restrict__ X, const float* __restrict__ c1W, const float* __restrict__ c1b,
    const float* __restrict__ c2W, const float* __restrict__ c2b,
    float* __restrict__ out, int n)
{
    __shared__ float w1[128 * 64];
    __shared__ float w2[64 * 8];
    __shared__ float b1s[64];
    __shared__ float b2s[8];
    int t = threadIdx.x;
    #pragma unroll
    for (int i = 0; i < 8; ++i) {
        int fi = t + 256 * i;   // 2048 float4 total
        *reinterpret_cast<float4*>(&w1[fi * 4]) = reinterpret_cast<const float4*>(c1W)[fi];
    }
    if (t < 128) reinterpret_cast<float4*>(w2)[t] = reinterpret_cast<const float4*>(c2W)[t];
    if (t < 64)  b1s[t] = c1b[t];
    if (t < 8)   b2s[t] = c2b[t];
    __syncthreads();

    int nw = gridDim.x * 4;
    int w  = blockIdx.x * 4 + (t >> 6);
    int j  = t & 63;
    for (int r = w; r < n; r += nw) {
        float hacc = b1s[j];
        #pragma unroll 8
        for (int k4 = 0; k4 < 32; ++k4) {
            float4 xv = *reinterpret_cast<const float4*>(X + (size_t)r * 128 + k4 * 4);
            hacc = fmaf(xv.x, w1[(k4 * 4 + 0) * 64 + j], hacc);
            hacc = fmaf(xv.y, w1[(k4 * 4 + 1) * 64 + j], hacc);
            hacc = fmaf(xv.z, w1[(k4 * 4 + 2) * 64 + j], hacc);
            hacc = fmaf(xv.w, w1[(k4 * 4 + 3) * 64 + j], hacc);
        }
        hacc = fmaxf(hacc, 0.f);
        float p[8];
        #pragma unroll
        for (int o = 0; o < 8; ++o) p[o] = hacc * w2[j * 8 + o];
        #pragma unroll
        for (int mm = 32; mm >= 1; mm >>= 1) {
            #pragma unroll
            for (int o = 0; o < 8; ++o) p[o] += __shfl_xor(p[o], mm);
        }
        float po = p[0];
        #pragma unroll
        for (int o = 1; o < 8; ++o) po = (j == o) ? p[o] : po;
        if (j < 8) out[(size_t)r * 8 + j] = po + b2s[j];
    }
}

// ---------------------------------------------------------------------------
extern "C" void kernel_launch(void* const* d_in, const int* in_sizes, int n_in,
                              void* d_out, int out_size, void* d_ws, size_t ws_size,
                              hipStream_t stream)
{
    const float* x_patent = (const float*)d_in[0];
    const int*   ei_cites = (const int*)d_in[2];
    const float* pn_w = (const float*)d_in[4];
    const float* pn_b = (const float*)d_in[5];
    const float* pl_W = (const float*)d_in[8];
    const float* pl_b = (const float*)d_in[9];
    const float* g1_W  = (const float*)d_in[12];
    const float* g1_as = (const float*)d_in[13];
    const float* g1_ad = (const float*)d_in[14];
    const float* g1_b  = (const float*)d_in[15];
    const float* g2_W  = (const float*)d_in[16];
    const float* g2_as = (const float*)d_in[17];
    const float* g2_ad = (const float*)d_in[18];
    const float* g2_b  = (const float*)d_in[19];
    const float* n1_w = (const float*)d_in[23];
    const float* n1_b = (const float*)d_in[24];
    const float* n3_w = (const float*)d_in[27];
    const float* n3_b = (const float*)d_in[28];
    const float* c1_W = (const float*)d_in[29];
    const float* c1_b = (const float*)d_in[30];
    const float* c2_W = (const float*)d_in[31];
    const float* c2_b = (const float*)d_in[32];

    const int NP = in_sizes[0] / 256;   // 100000
    const int EC = in_sizes[2] / 2;     // 1600000
    const int* e_src = ei_cites;
    const int* e_dst = ei_cites + EC;

    // workspace layout
    size_t off = 0;
    auto alloc = [&](size_t bytes) -> char* {
        char* p = (char*)d_ws + off;
        off += (bytes + 255) & ~(size_t)255;
        return p;
    };
    float* xp      = (float*)alloc((size_t)NP * 128 * 4);
    float* xph     = (float*)alloc((size_t)NP * 128 * 4);
    float* es      = (float*)alloc((size_t)NP * 4 * 4);
    float* ed      = (float*)alloc((size_t)NP * 4 * 4);
    float* meanb   = (float*)alloc((size_t)NP * 4);
    float* rstdb   = (float*)alloc((size_t)NP * 4);
    int*   deg     = (int*)alloc((size_t)NP * 4);
    int*   rowptr  = (int*)alloc((size_t)(NP + 1) * 4);
    int*   cursor  = (int*)alloc((size_t)NP * 4);
    int*   esrc    = (int*)alloc((size_t)EC * 4);
    int*   partial = (int*)alloc(256 * 4);
    (void)ws_size; (void)n_in; (void)out_size;

    int wpgrid = (NP + 3) / 4;            // wave-per-row kernels, 4 waves/block
    int egrid  = (EC + 255) / 256;
    int ggrid  = (NP + 63) / 64;
    int sgrid  = (NP + 1023) / 1024;      // scan blocks (98 for NP=100000)

    // --- CSR build (shared by both GAT layers)
    zero_int_kernel<<<(NP + 255) / 256, 256, 0, stream>>>(deg, NP);
    hist_kernel<<<egrid, 256, 0, stream>>>(e_dst, deg, EC);
    scan_blocks_kernel<<<sgrid, 1024, 0, stream>>>(deg, rowptr, partial, NP);
    scan_partials_kernel<<<1, 128, 0, stream>>>(partial, rowptr, sgrid, NP);
    add_offsets_kernel<<<sgrid, 1024, 0, stream>>>(partial, rowptr, cursor, NP);
    scatter_kernel<<<egrid, 256, 0, stream>>>(e_src, e_dst, cursor, esrc, EC);

    // --- xp = LN(x_patent) @ pl_W + pl_b
    ln_stats_kernel<<<wpgrid, 256, 0, stream>>>(x_patent, meanb, rstdb, NP);
    gemm_kernel<256, true, true, false><<<ggrid, 256, 0, stream>>>(
        x_patent, pl_W, pl_b, meanb, rstdb, pn_w, pn_b,
        nullptr, nullptr, nullptr, nullptr, xp, NP);

    // --- GAT layer 1 + relu + LN(n1) + residual (in place on xp)
    gemm_kernel<128, false, false, true><<<ggrid, 256, 0, stream>>>(
        xp, g1_W, nullptr, nullptr, nullptr, nullptr, nullptr,
        g1_as, g1_ad, es, ed, xph, NP);
    gat_aggregate_kernel<<<wpgrid, 256, 0, stream>>>(
        xph, es, ed, rowptr, esrc, g1_b, n1_w, n1_b, xp, NP);

    // --- GAT layer 2 + relu + LN(n3) + residual (in place on xp)
    gemm_kernel<128, false, false, true><<<ggrid, 256, 0, stream>>>(
        xp, g2_W, nullptr, nullptr, nullptr, nullptr, nullptr,
        g2_as, g2_ad, es, ed, xph, NP);
    gat_aggregate_kernel<<<wpgrid, 256, 0, stream>>>(
        xph, es, ed, rowptr, esrc, g2_b, n3_w, n3_b, xp, NP);

    // --- classifier head
    classifier_kernel<<<1024, 256, 0, stream>>>(
        xp, c1_W, c1_b, c2_W, c2_b, (float*)d_out, NP);
}

// Round 8
// 1065.518 us; speedup vs baseline: 1.2045x; 1.0020x over previous
//
#include <hip/hip_runtime.h>
#include <hip/hip_fp16.h>
#include <cstdint>

__device__ __forceinline__ float lrelu02(float x) {
    return fmaxf(x, 0.f) + 0.2f * fminf(x, 0.f);
}

// ---------------------------------------------------------------------------
// LN row stats for x_patent rows of length 256: one wave per row
// ---------------------------------------------------------------------------
__global__ __launch_bounds__(256) void ln_stats_kernel(
    const float* __restrict__ x, float* __restrict__ mean, float* __restrict__ rstd, int n)
{
    int wid  = (blockIdx.x * blockDim.x + threadIdx.x) >> 6;
    int lane = threadIdx.x & 63;
    if (wid >= n) return;
    float4 v = *reinterpret_cast<const float4*>(x + (size_t)wid * 256 + lane * 4);
    float s = v.x + v.y + v.z + v.w;
    float q = v.x * v.x + v.y * v.y + v.z * v.z + v.w * v.w;
    #pragma unroll
    for (int m = 32; m >= 1; m >>= 1) {
        s += __shfl_xor(s, m);
        q += __shfl_xor(q, m);
    }
    if (lane == 0) {
        float mu  = s * (1.0f / 256.0f);
        float var = q * (1.0f / 256.0f) - mu * mu;
        mean[wid] = mu;
        rstd[wid] = rsqrtf(var + 1e-5f);
    }
}

// ---------------------------------------------------------------------------
// CSR build: zero, histogram, 3-phase hierarchical scan, scatter
// ---------------------------------------------------------------------------
__global__ void zero_int_kernel(int* __restrict__ p, int n) {
    int i = blockIdx.x * blockDim.x + threadIdx.x;
    if (i < n) p[i] = 0;
}

__global__ void hist_kernel(const int* __restrict__ dst, int* __restrict__ deg, int ec) {
    int i = blockIdx.x * blockDim.x + threadIdx.x;
    if (i < ec) atomicAdd(&deg[dst[i]], 1);
}

// phase 1: per-1024-block local exclusive scan + block totals
__global__ __launch_bounds__(1024) void scan_blocks_kernel(
    const int* __restrict__ deg, int* __restrict__ rowptr, int* __restrict__ partials, int n)
{
    __shared__ int part[1024];
    int t = threadIdx.x;
    int i = blockIdx.x * 1024 + t;
    int v = (i < n) ? deg[i] : 0;
    part[t] = v;
    __syncthreads();
    #pragma unroll
    for (int off = 1; off < 1024; off <<= 1) {
        int u = (t >= off) ? part[t - off] : 0;
        __syncthreads();
        part[t] += u;
        __syncthreads();
    }
    if (i < n) rowptr[i] = part[t] - v;          // local exclusive prefix
    if (t == 1023) partials[blockIdx.x] = part[1023];
}

// phase 2: single small block scans the partials (nb <= 128)
__global__ __launch_bounds__(128) void scan_partials_kernel(
    int* __restrict__ partials, int* __restrict__ rowptr, int nb, int n)
{
    __shared__ int p[128];
    int t = threadIdx.x;
    int v = (t < nb) ? partials[t] : 0;
    p[t] = v;
    __syncthreads();
    #pragma unroll
    for (int off = 1; off < 128; off <<= 1) {
        int u = (t >= off) ? p[t - off] : 0;
        __syncthreads();
        p[t] += u;
        __syncthreads();
    }
    if (t < nb) partials[t] = p[t] - v;          // exclusive block offsets
    if (t == 127) rowptr[n] = p[127];            // total edge count
}

// phase 3: add block offsets; mirror into cursor
__global__ __launch_bounds__(1024) void add_offsets_kernel(
    const int* __restrict__ partials, int* __restrict__ rowptr, int* __restrict__ cursor, int n)
{
    int i = blockIdx.x * 1024 + threadIdx.x;
    if (i < n) {
        int r = rowptr[i] + partials[blockIdx.x];
        rowptr[i] = r;
        cursor[i] = r;
    }
}

__global__ void scatter_kernel(const int* __restrict__ src, const int* __restrict__ dst,
                               int* __restrict__ cursor, int* __restrict__ esrc, int ec)
{
    int i = blockIdx.x * blockDim.x + threadIdx.x;
    if (i < ec) {
        int d = dst[i];
        int pos = atomicAdd(&cursor[d], 1);
        esrc[pos] = src[i];
    }
}

// ---------------------------------------------------------------------------
// Tiled fp32 GEMM: Y[n,128] = op(X[n,K]) @ W[K,128] (+ bias)
// op = LayerNorm-on-load when LN_IN (per-row mean/rstd + per-col gamma/beta)
// ESED: also emit es/ed attention scalars from the fp32 accumulator tile.
// OUT_HALF: write Y as fp16 (gather-bandwidth optimization); es/ed stay fp32.
// BM=64, BN=128, BK=64, 256 threads, 8x4 accs/thread.
// ---------------------------------------------------------------------------
template <int K, bool LN_IN, bool BIAS, bool ESED, bool OUT_HALF>
__global__ __launch_bounds__(256) void gemm_kernel(
    const float* __restrict__ X, const float* __restrict__ W, const float* __restrict__ bias,
    const float* __restrict__ mean, const float* __restrict__ rstd,
    const float* __restrict__ gw, const float* __restrict__ gb,
    const float* __restrict__ a_s, const float* __restrict__ a_d,
    float* __restrict__ es, float* __restrict__ ed,
    void* __restrict__ Yv, int n)
{
    __shared__ float xs[64 * 68];    // 64 rows x 64 k, stride 68
    __shared__ float ws[64 * 132];   // 64 k  x 128 cols, stride 132
    int t  = threadIdx.x;
    int tx = t & 31;        // col group: cols tx*4 .. tx*4+3
    int ty = t >> 5;        // row group: rows ty*8 .. ty*8+7
    int row0 = blockIdx.x * 64;

    float acc[8][4];
    #pragma unroll
    for (int i = 0; i < 8; ++i)
        #pragma unroll
        for (int j = 0; j < 4; ++j) acc[i][j] = 0.f;

    for (int kt = 0; kt < K / 64; ++kt) {
        // X tile: 64x64 = 1024 float4
        #pragma unroll
        for (int i = 0; i < 4; ++i) {
            int fi = t + 256 * i;
            int r  = fi >> 4;
            int c  = (fi & 15) * 4;
            int gr = row0 + r;
            float4 v = make_float4(0.f, 0.f, 0.f, 0.f);
            if (gr < n) {
                v = *reinterpret_cast<const float4*>(X + (size_t)gr * K + kt * 64 + c);
                if (LN_IN) {
                    float mu = mean[gr];
                    float rs = rstd[gr];
                    float4 w4 = *reinterpret_cast<const float4*>(gw + kt * 64 + c);
                    float4 b4 = *reinterpret_cast<const float4*>(gb + kt * 64 + c);
                    v.x = (v.x - mu) * rs * w4.x + b4.x;
                    v.y = (v.y - mu) * rs * w4.y + b4.y;
                    v.z = (v.z - mu) * rs * w4.z + b4.z;
                    v.w = (v.w - mu) * rs * w4.w + b4.w;
                }
            }
            *reinterpret_cast<float4*>(&xs[r * 68 + c]) = v;
        }
        // W tile: 64x128 = 2048 float4
        #pragma unroll
        for (int i = 0; i < 8; ++i) {
            int fi = t + 256 * i;
            int r  = fi >> 5;
            int c  = (fi & 31) * 4;
            float4 v = *reinterpret_cast<const float4*>(W + (size_t)(kt * 64 + r) * 128 + c);
            *reinterpret_cast<float4*>(&ws[r * 132 + c]) = v;
        }
        __syncthreads();

        #pragma unroll
        for (int kk = 0; kk < 64; kk += 4) {
            float4 a4[8];
            #pragma unroll
            for (int i = 0; i < 8; ++i)
                a4[i] = *reinterpret_cast<const float4*>(&xs[(ty * 8 + i) * 68 + kk]);
            #pragma unroll
            for (int u = 0; u < 4; ++u) {
                float4 b = *reinterpret_cast<const float4*>(&ws[(kk + u) * 132 + tx * 4]);
                #pragma unroll
                for (int i = 0; i < 8; ++i) {
                    float a = (u == 0) ? a4[i].x : (u == 1) ? a4[i].y : (u == 2) ? a4[i].z : a4[i].w;
                    acc[i][0] = fmaf(a, b.x, acc[i][0]);
                    acc[i][1] = fmaf(a, b.y, acc[i][1]);
                    acc[i][2] = fmaf(a, b.z, acc[i][2]);
                    acc[i][3] = fmaf(a, b.w, acc[i][3]);
                }
            }
        }
        __syncthreads();
    }

    float4 bb = make_float4(0.f, 0.f, 0.f, 0.f);
    if (BIAS) bb = *reinterpret_cast<const float4*>(bias + tx * 4);
    #pragma unroll
    for (int i = 0; i < 8; ++i) {
        int gr = row0 + ty * 8 + i;
        if (gr < n) {
            float4 o;
            o.x = acc[i][0] + bb.x;
            o.y = acc[i][1] + bb.y;
            o.z = acc[i][2] + bb.z;
            o.w = acc[i][3] + bb.w;
            if (OUT_HALF) {
                union { __half2 h2[2]; uint2 u; } pk;
                pk.h2[0] = __floats2half2_rn(o.x, o.y);
                pk.h2[1] = __floats2half2_rn(o.z, o.w);
                *reinterpret_cast<uint2*>((__half*)Yv + (size_t)gr * 128 + tx * 4) = pk.u;
            } else {
                *reinterpret_cast<float4*>((float*)Yv + (size_t)gr * 128 + tx * 4) = o;
            }
        }
    }

    if (ESED) {
        // es[n,4] / ed[n,4]: per-head dot of the row with a_s/a_d (fp32 accs).
        float4 as4 = *reinterpret_cast<const float4*>(a_s + tx * 4);
        float4 ad4 = *reinterpret_cast<const float4*>(a_d + tx * 4);
        #pragma unroll
        for (int i = 0; i < 8; ++i) {
            float ps = acc[i][0] * as4.x + acc[i][1] * as4.y + acc[i][2] * as4.z + acc[i][3] * as4.w;
            float pd = acc[i][0] * ad4.x + acc[i][1] * ad4.y + acc[i][2] * ad4.z + acc[i][3] * ad4.w;
            #pragma unroll
            for (int m = 1; m <= 4; m <<= 1) {
                ps += __shfl_xor(ps, m);
                pd += __shfl_xor(pd, m);
            }
            int gr = row0 + ty * 8 + i;
            if ((tx & 7) == 0 && gr < n) {
                es[(size_t)gr * 4 + (tx >> 3)] = ps;
                ed[(size_t)gr * 4 + (tx >> 3)] = pd;
            }
        }
    }
}

// ---------------------------------------------------------------------------
// GAT aggregation over fp16 xph, two-phase lane-parallel edges, fused +bias,
// relu, LayerNorm, +residual. One wave per dst node.
// Lane l: head h = l>>4, edge-slot sub = l&15, owns output cols 2l, 2l+1.
// ---------------------------------------------------------------------------
__global__ __launch_bounds__(256) void gat_aggregate_kernel(
    const __half2* __restrict__ xph, const float* __restrict__ es, const float* __restrict__ ed,
    const int* __restrict__ rowptr, const int* __restrict__ esrc,
    const float* __restrict__ gbias, const float* __restrict__ lnw, const float* __restrict__ lnb,
    float* __restrict__ xp, int n)
{
    int d = (blockIdx.x * blockDim.x + threadIdx.x) >> 6;
    int l = threadIdx.x & 63;
    if (d >= n) return;
    int h   = l >> 4;
    int sub = l & 15;

    float edh   = ed[(size_t)d * 4 + h];
    float eself = lrelu02(es[(size_t)d * 4 + h] + edh);

    int jb = rowptr[d], je = rowptr[d + 1];

    // ---- phase 1: per-head max, lane-parallel (each lane strides by 16)
    float mh = eself;
    for (int j = jb + sub; j < je; j += 16) {
        int s = esrc[j];
        mh = fmaxf(mh, lrelu02(es[(size_t)s * 4 + h] + edh));
    }
    #pragma unroll
    for (int mm = 1; mm <= 8; mm <<= 1) mh = fmaxf(mh, __shfl_xor(mh, mm));
    // mh now uniform within each 16-lane head group

    // ---- phase 2: weights (1 exp per lane per 16-edge batch) + fp16 gather
    float wself = __expf(eself - mh);
    float2 xd   = __half22float2(xph[(size_t)d * 64 + l]);
    float2 acc  = make_float2(wself * xd.x, wself * xd.y);
    float  wsum = wself;

    int j0 = jb;
    for (; j0 + 16 <= je; j0 += 16) {
        int   myS = esrc[j0 + sub];
        float wl  = __expf(lrelu02(es[(size_t)myS * 4 + h] + edh) - mh);
        #pragma unroll
        for (int u = 0; u < 16; ++u) {
            int   s  = __shfl(myS, u);                  // uniform across wave
            float wj = __shfl(wl, (l & 48) + u);        // own head's weight
            float2 xv = __half22float2(xph[(size_t)s * 64 + l]);
            wsum += wj;
            acc.x = fmaf(wj, xv.x, acc.x);
            acc.y = fmaf(wj, xv.y, acc.y);
        }
    }
    if (j0 < je) {
        int   cnt = je - j0;                            // 1..15, wave-uniform
        int   myj = j0 + ((sub < cnt) ? sub : 0);       // clamp to valid edge
        int   myS = esrc[myj];
        float wl  = (sub < cnt)
                  ? __expf(lrelu02(es[(size_t)myS * 4 + h] + edh) - mh) : 0.f;
        for (int u = 0; u < cnt; ++u) {
            int   s  = __shfl(myS, u);
            float wj = __shfl(wl, (l & 48) + u);
            float2 xv = __half22float2(xph[(size_t)s * 64 + l]);
            wsum += wj;
            acc.x = fmaf(wj, xv.x, acc.x);
            acc.y = fmaf(wj, xv.y, acc.y);
        }
    }

    float inv = 1.0f / (wsum + 1e-16f);
    float2 gb2 = *reinterpret_cast<const float2*>(gbias + 2 * l);
    float v0 = fmaxf(fmaf(acc.x, inv, gb2.x), 0.f);
    float v1 = fmaxf(fmaf(acc.y, inv, gb2.y), 0.f);

    // LayerNorm over 128 (2 values/lane across the wave) + residual
    float sum = v0 + v1;
    float sq  = v0 * v0 + v1 * v1;
    #pragma unroll
    for (int mm = 32; mm >= 1; mm >>= 1) {
        sum += __shfl_xor(sum, mm);
        sq  += __shfl_xor(sq, mm);
    }
    float mu  = sum * (1.0f / 128.0f);
    float var = sq * (1.0f / 128.0f) - mu * mu;
    float rs  = rsqrtf(var + 1e-5f);
    float2 w2 = *reinterpret_cast<const float2*>(lnw + 2 * l);
    float2 b2 = *reinterpret_cast<const float2*>(lnb + 2 * l);
    float2 xin = *reinterpret_cast<const float2*>(xp + (size_t)d * 128 + 2 * l);
    float o0 = (v0 - mu) * rs * w2.x + b2.x + xin.x;
    float o1 = (v1 - mu) * rs * w2.y + b2.y + xin.y;
    *reinterpret_cast<float2*>(xp + (size_t)d * 128 + 2 * l) = make_float2(o0, o1);
}

// ---------------------------------------------------------------------------
// Classifier: out = relu(X @ c1W + c1b) @ c2W + c2b. One wave per row,
// c1W (32KB) + c2W staged in LDS per block, grid-stride over rows.
// ---------------------------------------------------------------------------
__global__ __launch_bounds__(256) void classifier_kernel(
    const float* __restrict__ X, const float* __restrict__ c1W, const float* __restrict__ c1b,
    const float* __restrict__ c2W, const float* __restrict__ c2b,
    float* __restrict__ out, int n)
{
    __shared__ float w1[128 * 64];
    __shared__ float w2[64 * 8];
    __shared__ float b1s[64];
    __shared__ float b2s[8];
    int t = threadIdx.x;
    #pragma unroll
    for (int i = 0; i < 8; ++i) {
        int fi = t + 256 * i;   // 2048 float4 total
        *reinterpret_cast<float4*>(&w1[fi * 4]) = reinterpret_cast<const float4*>(c1W)[fi];
    }
    if (t < 128) reinterpret_cast<float4*>(w2)[t] = reinterpret_cast<const float4*>(c2W)[t];
    if (t < 64)  b1s[t] = c1b[t];
    if (t < 8)   b2s[t] = c2b[t];
    __syncthreads();

    int nw = gridDim.x * 4;
    int w  = blockIdx.x * 4 + (t >> 6);
    int j  = t & 63;
    for (int r = w; r < n; r += nw) {
        float hacc = b1s[j];
        #pragma unroll 8
        for (int k4 = 0; k4 < 32; ++k4) {
            float4 xv = *reinterpret_cast<const float4*>(X + (size_t)r * 128 + k4 * 4);
            hacc = fmaf(xv.x, w1[(k4 * 4 + 0) * 64 + j], hacc);
            hacc = fmaf(xv.y, w1[(k4 * 4 + 1) * 64 + j], hacc);
            hacc = fmaf(xv.z, w1[(k4 * 4 + 2) * 64 + j], hacc);
            hacc = fmaf(xv.w, w1[(k4 * 4 + 3) * 64 + j], hacc);
        }
        hacc = fmaxf(hacc, 0.f);
        float p[8];
        #pragma unroll
        for (int o = 0; o < 8; ++o) p[o] = hacc * w2[j * 8 + o];
        #pragma unroll
        for (int mm = 32; mm >= 1; mm >>= 1) {
            #pragma unroll
            for (int o = 0; o < 8; ++o) p[o] += __shfl_xor(p[o], mm);
        }
        float po = p[0];
        #pragma unroll
        for (int o = 1; o < 8; ++o) po = (j == o) ? p[o] : po;
        if (j < 8) out[(size_t)r * 8 + j] = po + b2s[j];
    }
}

// ---------------------------------------------------------------------------
extern "C" void kernel_launch(void* const* d_in, const int* in_sizes, int n_in,
                              void* d_out, int out_size, void* d_ws, size_t ws_size,
                              hipStream_t stream)
{
    const float* x_patent = (const float*)d_in[0];
    const int*   ei_cites = (const int*)d_in[2];
    const float* pn_w = (const float*)d_in[4];
    const float* pn_b = (const float*)d_in[5];
    const float* pl_W = (const float*)d_in[8];
    const float* pl_b = (const float*)d_in[9];
    const float* g1_W  = (const float*)d_in[12];
    const float* g1_as = (const float*)d_in[13];
    const float* g1_ad = (const float*)d_in[14];
    const float* g1_b  = (const float*)d_in[15];
    const float* g2_W  = (const float*)d_in[16];
    const float* g2_as = (const float*)d_in[17];
    const float* g2_ad = (const float*)d_in[18];
    const float* g2_b  = (const float*)d_in[19];
    const float* n1_w = (const float*)d_in[23];
    const float* n1_b = (const float*)d_in[24];
    const float* n3_w = (const float*)d_in[27];
    const float* n3_b = (const float*)d_in[28];
    const float* c1_W = (const float*)d_in[29];
    const float* c1_b = (const float*)d_in[30];
    const float* c2_W = (const float*)d_in[31];
    const float* c2_b = (const float*)d_in[32];

    const int NP = in_sizes[0] / 256;   // 100000
    const int EC = in_sizes[2] / 2;     // 1600000
    const int* e_src = ei_cites;
    const int* e_dst = ei_cites + EC;

    // workspace layout
    size_t off = 0;
    auto alloc = [&](size_t bytes) -> char* {
        char* p = (char*)d_ws + off;
        off += (bytes + 255) & ~(size_t)255;
        return p;
    };
    float*   xp      = (float*)alloc((size_t)NP * 128 * 4);
    __half2* xph     = (__half2*)alloc((size_t)NP * 128 * 2);   // fp16 features
    float*   es      = (float*)alloc((size_t)NP * 4 * 4);
    float*   ed      = (float*)alloc((size_t)NP * 4 * 4);
    float*   meanb   = (float*)alloc((size_t)NP * 4);
    float*   rstdb   = (float*)alloc((size_t)NP * 4);
    int*     deg     = (int*)alloc((size_t)NP * 4);
    int*     rowptr  = (int*)alloc((size_t)(NP + 1) * 4);
    int*     cursor  = (int*)alloc((size_t)NP * 4);
    int*     esrc    = (int*)alloc((size_t)EC * 4);
    int*     partial = (int*)alloc(256 * 4);
    (void)ws_size; (void)n_in; (void)out_size;

    int wpgrid = (NP + 3) / 4;            // wave-per-row kernels, 4 waves/block
    int egrid  = (EC + 255) / 256;
    int ggrid  = (NP + 63) / 64;
    int sgrid  = (NP + 1023) / 1024;      // scan blocks (98 for NP=100000)

    // --- CSR build (shared by both GAT layers)
    zero_int_kernel<<<(NP + 255) / 256, 256, 0, stream>>>(deg, NP);
    hist_kernel<<<egrid, 256, 0, stream>>>(e_dst, deg, EC);
    scan_blocks_kernel<<<sgrid, 1024, 0, stream>>>(deg, rowptr, partial, NP);
    scan_partials_kernel<<<1, 128, 0, stream>>>(partial, rowptr, sgrid, NP);
    add_offsets_kernel<<<sgrid, 1024, 0, stream>>>(partial, rowptr, cursor, NP);
    scatter_kernel<<<egrid, 256, 0, stream>>>(e_src, e_dst, cursor, esrc, EC);

    // --- xp = LN(x_patent) @ pl_W + pl_b   (fp32 out)
    ln_stats_kernel<<<wpgrid, 256, 0, stream>>>(x_patent, meanb, rstdb, NP);
    gemm_kernel<256, true, true, false, false><<<ggrid, 256, 0, stream>>>(
        x_patent, pl_W, pl_b, meanb, rstdb, pn_w, pn_b,
        nullptr, nullptr, nullptr, nullptr, xp, NP);

    // --- GAT layer 1 (fp16 xph + fp32 es/ed) + relu + LN(n1) + residual
    gemm_kernel<128, false, false, true, true><<<ggrid, 256, 0, stream>>>(
        xp, g1_W, nullptr, nullptr, nullptr, nullptr, nullptr,
        g1_as, g1_ad, es, ed, xph, NP);
    gat_aggregate_kernel<<<wpgrid, 256, 0, stream>>>(
        xph, es, ed, rowptr, esrc, g1_b, n1_w, n1_b, xp, NP);

    // --- GAT layer 2 + relu + LN(n3) + residual
    gemm_kernel<128, false, false, true, true><<<ggrid, 256, 0, stream>>>(
        xp, g2_W, nullptr, nullptr, nullptr, nullptr, nullptr,
        g2_as, g2_ad, es, ed, xph, NP);
    gat_aggregate_kernel<<<wpgrid, 256, 0, stream>>>(
        xph, es, ed, rowptr, esrc, g2_b, n3_w, n3_b, xp, NP);

    // --- classifier head
    classifier_kernel<<<1024, 256, 0, stream>>>(
        xp, c1_W, c1_b, c2_W, c2_b, (float*)d_out, NP);
}